// Round 1
// baseline (565.839 us; speedup 1.0000x reference)
//
#include <hip/hip_runtime.h>

// Correlation layer (FlowNet-style), MAX_DISP=4 -> 81 displacements.
// out[b, d, y, x] = sum_c f1[b,c,y,x] * f2[b,c, y+dy-4, x+dx-4], d = dy*9+dx
//
// Decomposition:
//  - block: 128 threads = 4 y-rows x 32 x-groups; each thread owns 4 consecutive x.
//  - block computes 3 consecutive dy rows (dy-group g in {0,1,2}) for 64 channels
//    (channel split cs in {0..3}) -> 108 fp32 accumulators/thread.
//  - f2 tile (6 rows x 136 cols x 8 ch) staged in LDS; f1 loaded global->reg
//    (private to each thread). Combine channel splits with hw fp32 atomics.

namespace {
constexpr int B_ = 8, C_ = 256, H_ = 64, W_ = 128;
constexpr int SIDE = 9, ND = 81, PAD = 4;
constexpr int CC = 8;               // channels per LDS staging chunk
constexpr int DYG = 3;              // dy rows per block
constexpr int NG = 3;               // dy groups (3*3 = 9)
constexpr int CS = 4;               // channel splits
constexpr int CPB = C_ / CS;        // 64 channels per block
constexpr int NCH = CPB / CC;       // 8 chunks
constexpr int HT = 4;               // output y rows per block
constexpr int F2R = HT + DYG - 1;   // 6 f2 rows staged
constexpr int F2C = W_ + 2 * PAD;   // 136 cols (x in [-4, 132))
constexpr int NF4 = CC * F2R * (F2C / 4);  // 1632 float4 per chunk
}

__global__ __launch_bounds__(128, 3)
void corr_kernel(const float* __restrict__ f1, const float* __restrict__ f2,
                 float* __restrict__ out) {
  __shared__ __align__(16) float f2s[CC * F2R * F2C];

  const int t = threadIdx.x;
  const int txg = t & 31;   // x-group: covers x = txg*4 .. txg*4+3
  const int ty = t >> 5;    // 0..3
  const int ytile = blockIdx.x;        // 16 tiles of 4 rows
  const int g = blockIdx.y >> 2;       // dy group 0..2
  const int cs = blockIdx.y & 3;       // channel split 0..3
  const int b = blockIdx.z;

  const int y0base = ytile * HT;
  const int dybase = g * DYG;
  const int cbase = cs * CPB;

  float acc[DYG][SIDE][4];
#pragma unroll
  for (int r = 0; r < DYG; ++r)
#pragma unroll
    for (int dx = 0; dx < SIDE; ++dx)
#pragma unroll
      for (int p = 0; p < 4; ++p) acc[r][dx][p] = 0.f;

  for (int ch = 0; ch < NCH; ++ch) {
    const int c0 = cbase + ch * CC;
    if (ch) __syncthreads();  // previous chunk's compute must finish before overwrite

    // ---- stage f2 chunk: [CC][6 rows][136 cols], zero-filled halo ----
    for (int j = t; j < NF4; j += 128) {
      const int rc = j / 34;            // row-chunk 0..47
      const int i = j - rc * 34;        // float4 index in row, 0..33
      const int cc = rc / F2R;
      const int rt = rc - cc * F2R;
      const int yg = y0base + rt + dybase - PAD;
      float4 v = make_float4(0.f, 0.f, 0.f, 0.f);
      // i==0 -> x=-4..-1 (halo), i==33 -> x=128..131 (halo); i=1..32 fully in-bounds
      if (yg >= 0 && yg < H_ && i > 0 && i < 33) {
        v = *(const float4*)(f2 +
              (((size_t)(b * C_ + c0 + cc) * H_ + yg) * W_) + (i * 4 - 4));
      }
      *(float4*)&f2s[(cc * F2R + rt) * F2C + i * 4] = v;
    }
    __syncthreads();

    // ---- compute: per channel, 1 f1 float4 + 9 ds_read_b128 -> 108 FMA ----
    const float* f1p =
        f1 + (((size_t)(b * C_ + c0) * H_ + (y0base + ty)) * W_) + txg * 4;
#pragma unroll
    for (int cc = 0; cc < CC; ++cc) {
      const float4 a = *(const float4*)(f1p + (size_t)cc * (H_ * W_));
      const float av[4] = {a.x, a.y, a.z, a.w};
#pragma unroll
      for (int r = 0; r < DYG; ++r) {
        const float* rp = &f2s[(cc * F2R + ty + r) * F2C + txg * 4];
        const float4 w0 = *(const float4*)rp;
        const float4 w1 = *(const float4*)(rp + 4);
        const float4 w2 = *(const float4*)(rp + 8);
        const float wv[12] = {w0.x, w0.y, w0.z, w0.w, w1.x, w1.y, w1.z, w1.w,
                              w2.x, w2.y, w2.z, w2.w};
#pragma unroll
        for (int dx = 0; dx < SIDE; ++dx)
#pragma unroll
          for (int p = 0; p < 4; ++p)
            acc[r][dx][p] += av[p] * wv[dx + p];
      }
    }
  }

  // ---- epilogue: combine channel splits with hw fp32 atomics ----
  const int y = y0base + ty;
  const int x0 = txg * 4;
#pragma unroll
  for (int r = 0; r < DYG; ++r) {
#pragma unroll
    for (int dx = 0; dx < SIDE; ++dx) {
      const int d = (dybase + r) * SIDE + dx;
      float* po = out + ((size_t)(b * ND + d) * H_ + y) * W_ + x0;
#pragma unroll
      for (int p = 0; p < 4; ++p) {
        unsafeAtomicAdd(po + p, acc[r][dx][p]);  // global_atomic_add_f32
      }
    }
  }
}

extern "C" void kernel_launch(void* const* d_in, const int* in_sizes, int n_in,
                              void* d_out, int out_size, void* d_ws, size_t ws_size,
                              hipStream_t stream) {
  const float* f1 = (const float*)d_in[0];
  const float* f2 = (const float*)d_in[1];
  float* out = (float*)d_out;

  // d_out is poisoned 0xAA before every launch; atomics need zeros.
  hipMemsetAsync(out, 0, (size_t)out_size * sizeof(float), stream);

  dim3 grid(H_ / HT, NG * CS, B_);  // 16 x 12 x 8 = 1536 blocks
  corr_kernel<<<grid, 128, 0, stream>>>(f1, f2, out);
}

// Round 2
// 326.654 us; speedup vs baseline: 1.7322x; 1.7322x over previous
//
#include <hip/hip_runtime.h>

// Correlation layer (FlowNet-style), MAX_DISP=4 -> 81 displacements.
// out[b, d, y, x] = sum_c f1[b,c,y,x] * f2[b,c, y+dy-4, x+dx-4], d = dy*9+dx
//
// R2 design (no atomics — R1 was bound by 552 MB of atomic write traffic):
//  - one block per (ytile, dy, b): grid 16 x 9 x 8 = 1152 blocks, 128 threads.
//  - block = 4 y-rows x 32 x-groups; each thread owns 4 consecutive x.
//  - block accumulates ALL 256 channels (chunks of 8 staged in LDS), computes
//    9 dx for its single dy -> acc[9][4] per thread, written ONCE (float4).
//  - f2 chunk in LDS: [8 ch][4 rows][136 cols] = 17.4 KB. f1 global->reg.

namespace {
constexpr int B_ = 8, C_ = 256, H_ = 64, W_ = 128;
constexpr int SIDE = 9, ND = 81, PAD = 4;
constexpr int CC = 8;               // channels per LDS staging chunk
constexpr int NCH = C_ / CC;        // 32 chunks
constexpr int HT = 4;               // output y rows per block
constexpr int F2R = HT;             // 4 f2 rows staged (single dy)
constexpr int F2C = W_ + 2 * PAD;   // 136 cols (x in [-4, 132))
constexpr int NF4 = CC * F2R * (F2C / 4);  // 1088 float4 per chunk
}

__global__ __launch_bounds__(128, 4)
void corr_kernel(const float* __restrict__ f1, const float* __restrict__ f2,
                 float* __restrict__ out) {
  __shared__ __align__(16) float f2s[CC * F2R * F2C];

  const int t = threadIdx.x;
  const int txg = t & 31;   // x-group: covers x = txg*4 .. txg*4+3
  const int ty = t >> 5;    // 0..3
  const int ytile = blockIdx.x;        // 16 tiles of 4 rows
  const int dy = blockIdx.y;           // 0..8
  const int b = blockIdx.z;

  const int y0base = ytile * HT;

  float acc[SIDE][4];
#pragma unroll
  for (int dx = 0; dx < SIDE; ++dx)
#pragma unroll
    for (int p = 0; p < 4; ++p) acc[dx][p] = 0.f;

  for (int ch = 0; ch < NCH; ++ch) {
    const int c0 = ch * CC;
    if (ch) __syncthreads();  // previous chunk's compute must finish before overwrite

    // ---- stage f2 chunk: [CC][4 rows][136 cols], zero-filled halo ----
    for (int j = t; j < NF4; j += 128) {
      const int rc = j / 34;            // row-chunk 0..31
      const int i = j - rc * 34;        // float4 index in row, 0..33
      const int cc = rc >> 2;           // rc / F2R
      const int rt = rc & 3;            // rc % F2R
      const int yg = y0base + rt + dy - PAD;
      float4 v = make_float4(0.f, 0.f, 0.f, 0.f);
      // i==0 -> x=-4..-1 (halo), i==33 -> x=128..131 (halo); i=1..32 in-bounds
      if (yg >= 0 && yg < H_ && i > 0 && i < 33) {
        v = *(const float4*)(f2 +
              (((size_t)(b * C_ + c0 + cc) * H_ + yg) * W_) + (i * 4 - 4));
      }
      *(float4*)&f2s[(cc * F2R + rt) * F2C + i * 4] = v;
    }
    __syncthreads();

    // ---- compute: per channel, 1 f1 float4 + 3 ds_read_b128 -> 36 FMA ----
    const float* f1p =
        f1 + (((size_t)(b * C_ + c0) * H_ + (y0base + ty)) * W_) + txg * 4;
#pragma unroll
    for (int cc = 0; cc < CC; ++cc) {
      const float4 a = *(const float4*)(f1p + (size_t)cc * (H_ * W_));
      const float av[4] = {a.x, a.y, a.z, a.w};
      const float* rp = &f2s[(cc * F2R + ty) * F2C + txg * 4];
      const float4 w0 = *(const float4*)rp;
      const float4 w1 = *(const float4*)(rp + 4);
      const float4 w2 = *(const float4*)(rp + 8);
      const float wv[12] = {w0.x, w0.y, w0.z, w0.w, w1.x, w1.y, w1.z, w1.w,
                            w2.x, w2.y, w2.z, w2.w};
#pragma unroll
      for (int dx = 0; dx < SIDE; ++dx)
#pragma unroll
        for (int p = 0; p < 4; ++p)
          acc[dx][p] += av[p] * wv[dx + p];
    }
  }

  // ---- epilogue: each output element written exactly once, float4 stores ----
  const int y = y0base + ty;
  const int x0 = txg * 4;
#pragma unroll
  for (int dx = 0; dx < SIDE; ++dx) {
    const int d = dy * SIDE + dx;
    float* po = out + ((size_t)(b * ND + d) * H_ + y) * W_ + x0;
    *(float4*)po = make_float4(acc[dx][0], acc[dx][1], acc[dx][2], acc[dx][3]);
  }
}

extern "C" void kernel_launch(void* const* d_in, const int* in_sizes, int n_in,
                              void* d_out, int out_size, void* d_ws, size_t ws_size,
                              hipStream_t stream) {
  const float* f1 = (const float*)d_in[0];
  const float* f2 = (const float*)d_in[1];
  float* out = (float*)d_out;

  dim3 grid(H_ / HT, SIDE, B_);  // 16 x 9 x 8 = 1152 blocks
  corr_kernel<<<grid, 128, 0, stream>>>(f1, f2, out);
}